// Round 18
// baseline (54.590 us; speedup 1.0000x reference)
//
#include <hip/hip_runtime.h>

#define N_TOTAL 8192
#define B_HALF  4096
#define D_DIM   256
#define BM      128
#define NB      64                    // 128-row strips
#define NSLOT   80                    // 16 row-chunk slots + 64 col slots
#define MAXT    4                     // max B tiles (bj strips) per block

typedef __attribute__((ext_vector_type(4))) float f32x4;
typedef __attribute__((ext_vector_type(4))) int   int4v;
typedef __attribute__((ext_vector_type(8))) int   int8v;   // 32 fp8 = K=128 frag

// async global->LDS, 16B per lane (dest = wave-uniform base + lane*16)
#define GLOAD16(src, dst) __builtin_amdgcn_global_load_lds( \
    (const __attribute__((address_space(1))) unsigned int*)(src), \
    (__attribute__((address_space(3))) unsigned int*)(dst), 16, 0, 0)

// OCP e4m3fn decode (bias 7, 3-bit mantissa, subnormal scale 2^-6)
__device__ __forceinline__ float fp8_to_f32(unsigned b) {
    unsigned s = b >> 7, e = (b >> 3) & 15, m = b & 7;
    float mag = e ? (float)(8 + m) * __int_as_float((int)((e + 117) << 23))
                  : (float)m * 0.001953125f;            // m * 2^-9
    return s ? -mag : mag;
}

// ---------------------------------------------------------------------------
// Kernel 1: fused normalize + positive-pair sim + fp8 self-similarity.
// One WAVE per pair i.  zn8 rows natural k-order fp8, scaled by sqrt(2) so
// dot = 2*cos = s.  pos fp32 (unrounded); self = fp8-rounded self-dot so lse
// subtracts the diagonal exactly -> simexp is branch-light.
// ---------------------------------------------------------------------------
__global__ __launch_bounds__(256) void nrmpos_kernel(const float* __restrict__ z1,
                                                     const float* __restrict__ z2,
                                                     unsigned char* __restrict__ zn8,
                                                     float* __restrict__ pos,
                                                     float* __restrict__ self) {
    int i    = (blockIdx.x * 256 + threadIdx.x) >> 6;   // pair 0..4095
    int lane = threadIdx.x & 63;
    float4 a = reinterpret_cast<const float4*>(z1 + (size_t)i * D_DIM)[lane];
    float4 b = reinterpret_cast<const float4*>(z2 + (size_t)i * D_DIM)[lane];
    float ssa = a.x * a.x + a.y * a.y + a.z * a.z + a.w * a.w;
    float ssb = b.x * b.x + b.y * b.y + b.z * b.z + b.w * b.w;
    float dab = a.x * b.x + a.y * b.y + a.z * b.z + a.w * b.w;
#pragma unroll
    for (int m = 32; m >= 1; m >>= 1) {
        ssa += __shfl_xor(ssa, m);
        ssb += __shfl_xor(ssb, m);
        dab += __shfl_xor(dab, m);
    }
    float inva = 1.0f / fmaxf(sqrtf(ssa), 1e-8f);
    float invb = 1.0f / fmaxf(sqrtf(ssb), 1e-8f);
    float sa = 1.4142135623730951f * inva;
    float sb = 1.4142135623730951f * invb;
    int pa = __builtin_amdgcn_cvt_pk_fp8_f32(a.x * sa, a.y * sa, 0, false);
    pa     = __builtin_amdgcn_cvt_pk_fp8_f32(a.z * sa, a.w * sa, pa, true);
    int pb = __builtin_amdgcn_cvt_pk_fp8_f32(b.x * sb, b.y * sb, 0, false);
    pb     = __builtin_amdgcn_cvt_pk_fp8_f32(b.z * sb, b.w * sb, pb, true);
    float sa8 = 0.0f, sb8 = 0.0f;
#pragma unroll
    for (int u = 0; u < 4; ++u) {
        float da = fp8_to_f32((unsigned)(pa >> (8 * u)) & 0xff);
        float db = fp8_to_f32((unsigned)(pb >> (8 * u)) & 0xff);
        sa8 += da * da;
        sb8 += db * db;
    }
#pragma unroll
    for (int m = 32; m >= 1; m >>= 1) {
        sa8 += __shfl_xor(sa8, m);
        sb8 += __shfl_xor(sb8, m);
    }
    *reinterpret_cast<int*>(zn8 + (size_t)i * D_DIM + lane * 4)            = pa;
    *reinterpret_cast<int*>(zn8 + (size_t)(i + B_HALF) * D_DIM + lane * 4) = pb;
    if (lane == 0) {
        float pp = 2.0f * dab * inva * invb;
        pos[i]           = pp;
        pos[i + B_HALF]  = pp;
        self[i]          = sa8;
        self[i + B_HALF] = sb8;
    }
}

// ---------------------------------------------------------------------------
// Kernel 2: SYMMETRIC fused sim+exp (R17, byte-identical — passed absmax 0.0).
// Upper-triangle only: block (bi, c) owns tiles (bi, bj), bj = bi+4c .. +NT-1
// (NT = min(4, 64-bj0)) -> 2080 tiles over 544 real blocks.
//   rowacc -> partials[c][bi*128 + r]          (all tiles of the block)
//   colacc -> partials[16+bi][bj*128 + col]    (off-diag tiles, s_ji = s_ij)
// NO memset needed: lse sums exactly the written slots (see lse_kernel).
// Engine: MX-scaled MFMA 16x16x128 fp8 (scale=1.0 exact), 4 waves (2x2),
// A-frags in registers, B dbuf 2x32 KB, 1 barrier/tile, proven B swizzle,
// __expf, MFMA -> barrier -> stage -> exp order (R12 champion schedule).
// ---------------------------------------------------------------------------
__global__ __launch_bounds__(256, 2) void simexp_kernel(const unsigned char* __restrict__ zn8,
                                                        float* __restrict__ partials) {
    __shared__ __attribute__((aligned(16))) unsigned char lB[2][BM * D_DIM];  // 64 KB
    __shared__ float red[4][64];
    __shared__ float redc[MAXT][4][64];   // per-tile col sums, read post-loop

    const int bi  = blockIdx.x;           // row strip (0..63), FAST axis
    const int c   = blockIdx.y;           // chunk (0..15)
    const int bj0 = bi + 4 * c;
    if (bj0 >= NB) return;                // dead block (uniform exit)
    const int NT  = (NB - bj0) < MAXT ? (NB - bj0) : MAXT;

    const int tid  = threadIdx.x;
    const int lane = tid & 63;
    const int wid  = tid >> 6;
    const int wr   = wid >> 1;            // wave row 0..1
    const int wc   = wid & 1;             // wave col 0..1
    const int lrow16 = lane & 15;
    const int kgrp   = lane >> 4;         // 0..3  (k-group of 32 within 128)

    const unsigned char* Abase = zn8 + (size_t)bi * BM * D_DIM;

    // staging: 2048 granules of 16B per 32KB tile, 8 per thread, src-swizzled
    int soff[8];
#pragma unroll
    for (int u = 0; u < 8; ++u) {
        const int g = tid + u * 256;
        const int r = g >> 4, cc = g & 15;
        soff[u] = r * D_DIM + ((cc ^ (r & 15)) << 4);
    }
    auto stageB = [&](int t, int buf) {
        const unsigned char* Bb = zn8 + (size_t)(bj0 + t) * BM * D_DIM;
#pragma unroll
        for (int u = 0; u < 8; ++u)
            GLOAD16(Bb + soff[u], lB[buf] + ((tid + u * 256) << 4));
    };

    // swizzled 32B frag load: row-local cells (ck*8 + kgrp*2 + {0,1}) ^ lrow16
    auto load32 = [&](const unsigned char* base, int row, int ck) -> int8v {
        const int c0 = ck * 8 + kgrp * 2;
        int4v lo = *reinterpret_cast<const int4v*>(
            base + row * D_DIM + (((c0 + 0) ^ lrow16) << 4));
        int4v hi = *reinterpret_cast<const int4v*>(
            base + row * D_DIM + (((c0 + 1) ^ lrow16) << 4));
        int8v r8;
        r8[0] = lo[0]; r8[1] = lo[1]; r8[2] = lo[2]; r8[3] = lo[3];
        r8[4] = hi[0]; r8[5] = hi[1]; r8[6] = hi[2]; r8[7] = hi[3];
        return r8;
    };

    // ---- prologue: A -> lB[1], B0 -> lB[0] ----
#pragma unroll
    for (int u = 0; u < 8; ++u)
        GLOAD16(Abase + soff[u], lB[1] + ((tid + u * 256) << 4));
    stageB(0, 0);
    __syncthreads();                      // A + B0 landed

    // hoist all 8 A fragments to registers (aF[ck][mt], 64 VGPR)
    int8v aF[2][4];
#pragma unroll
    for (int ck = 0; ck < 2; ++ck)
#pragma unroll
        for (int mt = 0; mt < 4; ++mt)
            aF[ck][mt] = load32(lB[1], wr * 64 + mt * 16 + lrow16, ck);
    __syncthreads();                      // all waves done: lB[1] free
    if (NT > 1) stageB(1, 1);             // B1 in flight across tile 0 compute

    f32x4 acc[4][4];
    float rowacc[4][4];
#pragma unroll
    for (int mt = 0; mt < 4; ++mt)
#pragma unroll
        for (int nt = 0; nt < 4; ++nt) { acc[mt][nt] = (f32x4)(0.0f); rowacc[mt][nt] = 0.0f; }

    for (int t = 0; t < NT; ++t) {
        const unsigned char* Bl = lB[t & 1];

        // ---- pure LDS+MFMA phase: 2 k-chunks x 16 mfma_scale ----
#pragma unroll
        for (int ck = 0; ck < 2; ++ck) {
            int8v bF[4];
#pragma unroll
            for (int nt = 0; nt < 4; ++nt)
                bF[nt] = load32(Bl, wc * 64 + nt * 16 + lrow16, ck);
#pragma unroll
            for (int mt = 0; mt < 4; ++mt)
#pragma unroll
                for (int nt = 0; nt < 4; ++nt)
                    acc[mt][nt] = __builtin_amdgcn_mfma_scale_f32_16x16x128_f8f6f4(
                        aF[ck][mt], bF[nt], acc[mt][nt],
                        0, 0, 0, 127, 0, 127);
        }

        if (t + 1 < NT) __syncthreads();      // B(t+1) landed; buf(t) reads done
        if (t + 2 < NT) stageB(t + 2, t & 1); // refill freed buffer

        // ---- register-only exp epilogue (covers in-flight stage) ----
        float cs[4] = {0.0f, 0.0f, 0.0f, 0.0f};
#pragma unroll
        for (int mt = 0; mt < 4; ++mt) {
#pragma unroll
            for (int r = 0; r < 4; ++r) {
                float s = 0.0f;
#pragma unroll
                for (int nt = 0; nt < 4; ++nt) {
                    float e = __expf(acc[mt][nt][r] - 2.0f);
                    s += e;
                    cs[nt] += e;
                }
                rowacc[mt][r] += s;
            }
#pragma unroll
            for (int nt = 0; nt < 4; ++nt) acc[mt][nt] = (f32x4)(0.0f);
        }
        // colacc: reduce over kgrp (rows), stash per-tile (diag tile skipped)
        if (!(c == 0 && t == 0)) {
#pragma unroll
            for (int nt = 0; nt < 4; ++nt) {
                float cc2 = cs[nt];
                cc2 += __shfl_xor(cc2, 16);
                cc2 += __shfl_xor(cc2, 32);
                if (kgrp == 0) redc[t][wid][nt * 16 + lrow16] = cc2;
            }
        }
    }

    // ---- block-end: rowacc reduce + all global writes ----
#pragma unroll
    for (int mt = 0; mt < 4; ++mt)
#pragma unroll
        for (int r = 0; r < 4; ++r) {
            float v = rowacc[mt][r];
            v += __shfl_xor(v, 1); v += __shfl_xor(v, 2);
            v += __shfl_xor(v, 4); v += __shfl_xor(v, 8);
            if (lrow16 == 0) red[wid][mt * 16 + kgrp * 4 + r] = v;
        }
    __syncthreads();                      // red + all redc visible
    if (tid < BM) {                       // row sums -> slot c
        const int h = tid >> 6, l = tid & 63;
        partials[(size_t)c * N_TOTAL + bi * BM + tid] = red[h * 2][l] + red[h * 2 + 1][l];
    } else {                              // col sums -> slot 16+bi (per tile)
        const int col = tid - BM;         // 0..127
        const int wcc = col >> 6, l = col & 63;
        for (int t = 0; t < NT; ++t) {
            if (c == 0 && t == 0) continue;   // diag tile: no colacc
            partials[(size_t)(16 + bi) * N_TOTAL + (bj0 + t) * BM + col] =
                redc[t][wcc][l] + redc[t][2 + wcc][l];
        }
    }
}

// ---------------------------------------------------------------------------
// Kernel 3: per-row lse - pos.  Sums EXACTLY the deterministically-written
// slots for this row's strip R = row/128 (no memset needed):
//   row-chunk slots c = 0 .. (63-R)>>2   (block (R,c) exists iff R+4c<=63)
//   col slots 16+bi for bi = 0 .. R-1    (every pair (bi,R), bi<R)
// Then subtracts the fp8 diagonal term (self) exactly.
// ---------------------------------------------------------------------------
__global__ __launch_bounds__(256) void lse_kernel(const float* __restrict__ partials,
                                                  const float* __restrict__ pos,
                                                  const float* __restrict__ self,
                                                  float* __restrict__ bsums) {
    int tid = threadIdx.x;
    int row = blockIdx.x * 256 + tid;
    const int R = row >> 7;               // strip index
    float s = 0.0f;
    const int cmax = (63 - R) >> 2;
    for (int c = 0; c <= cmax; ++c) s += partials[(size_t)c * N_TOTAL + row];
    for (int b = 0; b < R; ++b)     s += partials[(size_t)(16 + b) * N_TOTAL + row];
    s -= __expf(self[row] - 2.0f);        // remove diagonal contribution
    float v = 2.0f + logf(s) - pos[row];
#pragma unroll
    for (int m = 32; m >= 1; m >>= 1) v += __shfl_xor(v, m);
    __shared__ float wsum[4];
    if ((tid & 63) == 0) wsum[tid >> 6] = v;
    __syncthreads();
    if (tid == 0) bsums[blockIdx.x] = wsum[0] + wsum[1] + wsum[2] + wsum[3];
}

__global__ void final_kernel(const float* __restrict__ bsums, float* __restrict__ out) {
    int tid = threadIdx.x;                // 64 threads
    float v = (tid < N_TOTAL / 256) ? bsums[tid] : 0.0f;
#pragma unroll
    for (int m = 32; m >= 1; m >>= 1) v += __shfl_xor(v, m);
    if (tid == 0) out[0] = v * (1.0f / (float)N_TOTAL);
}

// ---------------------------------------------------------------------------
extern "C" void kernel_launch(void* const* d_in, const int* in_sizes, int n_in,
                              void* d_out, int out_size, void* d_ws, size_t ws_size,
                              hipStream_t stream) {
    const float* z1 = (const float*)d_in[0];
    const float* z2 = (const float*)d_in[1];
    float* out = (float*)d_out;

    char* ws = (char*)d_ws;
    unsigned char* zn8 = (unsigned char*)ws;                               // 2 MB
    size_t off = (size_t)N_TOTAL * D_DIM;
    float* pos = (float*)(ws + off);                                       // 32 KB
    off += (size_t)N_TOTAL * sizeof(float);
    float* self = (float*)(ws + off);                                      // 32 KB
    off += (size_t)N_TOTAL * sizeof(float);
    float* partials = (float*)(ws + off);                                  // 2.62 MB
    off += (size_t)NSLOT * N_TOTAL * sizeof(float);
    float* bsums = (float*)(ws + off);                                     // 128 B

    nrmpos_kernel<<<B_HALF / 4, 256, 0, stream>>>(z1, z2, zn8, pos, self);
    simexp_kernel<<<dim3(NB, 16), 256, 0, stream>>>(zn8, partials);
    lse_kernel<<<N_TOTAL / 256, 256, 0, stream>>>(partials, pos, self, bsums);
    final_kernel<<<1, 64, 0, stream>>>(bsums, out);
}

// Round 19
// 44.203 us; speedup vs baseline: 1.2350x; 1.2350x over previous
//
#include <hip/hip_runtime.h>

#define N_TOTAL 8192
#define B_HALF  4096
#define D_DIM   256
#define BM      128
#define NB      64                    // 128-row strips
#define NSLOT   80                    // 16 row-chunk slots + 64 col slots
#define MAXT    4                     // max B tiles (bj strips) per block

typedef __attribute__((ext_vector_type(4))) float f32x4;
typedef __attribute__((ext_vector_type(4))) int   int4v;
typedef __attribute__((ext_vector_type(8))) int   int8v;   // 32 fp8 = K=128 frag

// async global->LDS, 16B per lane (dest = wave-uniform base + lane*16)
#define GLOAD16(src, dst) __builtin_amdgcn_global_load_lds( \
    (const __attribute__((address_space(1))) unsigned int*)(src), \
    (__attribute__((address_space(3))) unsigned int*)(dst), 16, 0, 0)

// OCP e4m3fn decode (bias 7, 3-bit mantissa, subnormal scale 2^-6)
__device__ __forceinline__ float fp8_to_f32(unsigned b) {
    unsigned s = b >> 7, e = (b >> 3) & 15, m = b & 7;
    float mag = e ? (float)(8 + m) * __int_as_float((int)((e + 117) << 23))
                  : (float)m * 0.001953125f;            // m * 2^-9
    return s ? -mag : mag;
}

// ---------------------------------------------------------------------------
// Kernel 1: fused normalize + positive-pair sim + fp8 self-similarity
// + partials ZEROING (replaces the 40us runtime hipMemsetAsync fill, R17
// lesson: rocclr's small-fill kernel is fixed-overhead-bound).
// One WAVE per pair i.  zn8 rows natural k-order fp8, scaled by sqrt(2) so
// dot = 2*cos = s.  pos fp32 (unrounded); self = fp8-rounded self-dot so lse
// subtracts the diagonal exactly.  Zeroed partials cells are disjoint from
// simexp's writes; nrmpos -> simexp -> lse are stream-ordered.
// ---------------------------------------------------------------------------
__global__ __launch_bounds__(256) void nrmpos_kernel(const float* __restrict__ z1,
                                                     const float* __restrict__ z2,
                                                     unsigned char* __restrict__ zn8,
                                                     float* __restrict__ pos,
                                                     float* __restrict__ self,
                                                     float* __restrict__ partials) {
    // zero partials: 655360 floats = 163840 float4, threads 0..262143
    int t0 = blockIdx.x * 256 + threadIdx.x;
    if (t0 < NSLOT * N_TOTAL / 4)
        reinterpret_cast<f32x4*>(partials)[t0] = (f32x4)(0.0f);

    int i    = t0 >> 6;                  // pair 0..4095
    int lane = threadIdx.x & 63;
    float4 a = reinterpret_cast<const float4*>(z1 + (size_t)i * D_DIM)[lane];
    float4 b = reinterpret_cast<const float4*>(z2 + (size_t)i * D_DIM)[lane];
    float ssa = a.x * a.x + a.y * a.y + a.z * a.z + a.w * a.w;
    float ssb = b.x * b.x + b.y * b.y + b.z * b.z + b.w * b.w;
    float dab = a.x * b.x + a.y * b.y + a.z * b.z + a.w * b.w;
#pragma unroll
    for (int m = 32; m >= 1; m >>= 1) {
        ssa += __shfl_xor(ssa, m);
        ssb += __shfl_xor(ssb, m);
        dab += __shfl_xor(dab, m);
    }
    float inva = 1.0f / fmaxf(sqrtf(ssa), 1e-8f);
    float invb = 1.0f / fmaxf(sqrtf(ssb), 1e-8f);
    float sa = 1.4142135623730951f * inva;
    float sb = 1.4142135623730951f * invb;
    int pa = __builtin_amdgcn_cvt_pk_fp8_f32(a.x * sa, a.y * sa, 0, false);
    pa     = __builtin_amdgcn_cvt_pk_fp8_f32(a.z * sa, a.w * sa, pa, true);
    int pb = __builtin_amdgcn_cvt_pk_fp8_f32(b.x * sb, b.y * sb, 0, false);
    pb     = __builtin_amdgcn_cvt_pk_fp8_f32(b.z * sb, b.w * sb, pb, true);
    float sa8 = 0.0f, sb8 = 0.0f;
#pragma unroll
    for (int u = 0; u < 4; ++u) {
        float da = fp8_to_f32((unsigned)(pa >> (8 * u)) & 0xff);
        float db = fp8_to_f32((unsigned)(pb >> (8 * u)) & 0xff);
        sa8 += da * da;
        sb8 += db * db;
    }
#pragma unroll
    for (int m = 32; m >= 1; m >>= 1) {
        sa8 += __shfl_xor(sa8, m);
        sb8 += __shfl_xor(sb8, m);
    }
    *reinterpret_cast<int*>(zn8 + (size_t)i * D_DIM + lane * 4)            = pa;
    *reinterpret_cast<int*>(zn8 + (size_t)(i + B_HALF) * D_DIM + lane * 4) = pb;
    if (lane == 0) {
        float pp = 2.0f * dab * inva * invb;
        pos[i]           = pp;
        pos[i + B_HALF]  = pp;
        self[i]          = sa8;
        self[i + B_HALF] = sb8;
    }
}

// ---------------------------------------------------------------------------
// Kernel 2: SYMMETRIC fused sim+exp (byte-identical to R17/R18 — absmax 0.0).
// Upper-triangle only: block (bi, c) owns tiles (bi, bj), bj = bi+4c .. +NT-1
// (NT = min(4, 64-bj0)) -> 2080 tiles over 544 real blocks.
//   rowacc -> partials[c][bi*128 + r]          (all tiles of the block)
//   colacc -> partials[16+bi][bj*128 + col]    (off-diag tiles, s_ji = s_ij)
// Engine: MX-scaled MFMA 16x16x128 fp8 (scale=1.0 exact), 4 waves (2x2),
// A-frags in registers, B dbuf 2x32 KB, 1 barrier/tile, proven B swizzle,
// __expf, MFMA -> barrier -> stage -> exp order (R12 champion schedule).
// ---------------------------------------------------------------------------
__global__ __launch_bounds__(256, 2) void simexp_kernel(const unsigned char* __restrict__ zn8,
                                                        float* __restrict__ partials) {
    __shared__ __attribute__((aligned(16))) unsigned char lB[2][BM * D_DIM];  // 64 KB
    __shared__ float red[4][64];
    __shared__ float redc[MAXT][4][64];   // per-tile col sums, read post-loop

    const int bi  = blockIdx.x;           // row strip (0..63), FAST axis
    const int c   = blockIdx.y;           // chunk (0..15)
    const int bj0 = bi + 4 * c;
    if (bj0 >= NB) return;                // dead block (uniform exit)
    const int NT  = (NB - bj0) < MAXT ? (NB - bj0) : MAXT;

    const int tid  = threadIdx.x;
    const int lane = tid & 63;
    const int wid  = tid >> 6;
    const int wr   = wid >> 1;            // wave row 0..1
    const int wc   = wid & 1;             // wave col 0..1
    const int lrow16 = lane & 15;
    const int kgrp   = lane >> 4;         // 0..3  (k-group of 32 within 128)

    const unsigned char* Abase = zn8 + (size_t)bi * BM * D_DIM;

    // staging: 2048 granules of 16B per 32KB tile, 8 per thread, src-swizzled
    int soff[8];
#pragma unroll
    for (int u = 0; u < 8; ++u) {
        const int g = tid + u * 256;
        const int r = g >> 4, cc = g & 15;
        soff[u] = r * D_DIM + ((cc ^ (r & 15)) << 4);
    }
    auto stageB = [&](int t, int buf) {
        const unsigned char* Bb = zn8 + (size_t)(bj0 + t) * BM * D_DIM;
#pragma unroll
        for (int u = 0; u < 8; ++u)
            GLOAD16(Bb + soff[u], lB[buf] + ((tid + u * 256) << 4));
    };

    // swizzled 32B frag load: row-local cells (ck*8 + kgrp*2 + {0,1}) ^ lrow16
    auto load32 = [&](const unsigned char* base, int row, int ck) -> int8v {
        const int c0 = ck * 8 + kgrp * 2;
        int4v lo = *reinterpret_cast<const int4v*>(
            base + row * D_DIM + (((c0 + 0) ^ lrow16) << 4));
        int4v hi = *reinterpret_cast<const int4v*>(
            base + row * D_DIM + (((c0 + 1) ^ lrow16) << 4));
        int8v r8;
        r8[0] = lo[0]; r8[1] = lo[1]; r8[2] = lo[2]; r8[3] = lo[3];
        r8[4] = hi[0]; r8[5] = hi[1]; r8[6] = hi[2]; r8[7] = hi[3];
        return r8;
    };

    // ---- prologue: A -> lB[1], B0 -> lB[0] ----
#pragma unroll
    for (int u = 0; u < 8; ++u)
        GLOAD16(Abase + soff[u], lB[1] + ((tid + u * 256) << 4));
    stageB(0, 0);
    __syncthreads();                      // A + B0 landed

    // hoist all 8 A fragments to registers (aF[ck][mt], 64 VGPR)
    int8v aF[2][4];
#pragma unroll
    for (int ck = 0; ck < 2; ++ck)
#pragma unroll
        for (int mt = 0; mt < 4; ++mt)
            aF[ck][mt] = load32(lB[1], wr * 64 + mt * 16 + lrow16, ck);
    __syncthreads();                      // all waves done: lB[1] free
    if (NT > 1) stageB(1, 1);             // B1 in flight across tile 0 compute

    f32x4 acc[4][4];
    float rowacc[4][4];
#pragma unroll
    for (int mt = 0; mt < 4; ++mt)
#pragma unroll
        for (int nt = 0; nt < 4; ++nt) { acc[mt][nt] = (f32x4)(0.0f); rowacc[mt][nt] = 0.0f; }

    for (int t = 0; t < NT; ++t) {
        const unsigned char* Bl = lB[t & 1];

        // ---- pure LDS+MFMA phase: 2 k-chunks x 16 mfma_scale ----
#pragma unroll
        for (int ck = 0; ck < 2; ++ck) {
            int8v bF[4];
#pragma unroll
            for (int nt = 0; nt < 4; ++nt)
                bF[nt] = load32(Bl, wc * 64 + nt * 16 + lrow16, ck);
#pragma unroll
            for (int mt = 0; mt < 4; ++mt)
#pragma unroll
                for (int nt = 0; nt < 4; ++nt)
                    acc[mt][nt] = __builtin_amdgcn_mfma_scale_f32_16x16x128_f8f6f4(
                        aF[ck][mt], bF[nt], acc[mt][nt],
                        0, 0, 0, 127, 0, 127);
        }

        if (t + 1 < NT) __syncthreads();      // B(t+1) landed; buf(t) reads done
        if (t + 2 < NT) stageB(t + 2, t & 1); // refill freed buffer

        // ---- register-only exp epilogue (covers in-flight stage) ----
        float cs[4] = {0.0f, 0.0f, 0.0f, 0.0f};
#pragma unroll
        for (int mt = 0; mt < 4; ++mt) {
#pragma unroll
            for (int r = 0; r < 4; ++r) {
                float s = 0.0f;
#pragma unroll
                for (int nt = 0; nt < 4; ++nt) {
                    float e = __expf(acc[mt][nt][r] - 2.0f);
                    s += e;
                    cs[nt] += e;
                }
                rowacc[mt][r] += s;
            }
#pragma unroll
            for (int nt = 0; nt < 4; ++nt) acc[mt][nt] = (f32x4)(0.0f);
        }
        // colacc: reduce over kgrp (rows), stash per-tile (diag tile skipped)
        if (!(c == 0 && t == 0)) {
#pragma unroll
            for (int nt = 0; nt < 4; ++nt) {
                float cc2 = cs[nt];
                cc2 += __shfl_xor(cc2, 16);
                cc2 += __shfl_xor(cc2, 32);
                if (kgrp == 0) redc[t][wid][nt * 16 + lrow16] = cc2;
            }
        }
    }

    // ---- block-end: rowacc reduce + all global writes ----
#pragma unroll
    for (int mt = 0; mt < 4; ++mt)
#pragma unroll
        for (int r = 0; r < 4; ++r) {
            float v = rowacc[mt][r];
            v += __shfl_xor(v, 1); v += __shfl_xor(v, 2);
            v += __shfl_xor(v, 4); v += __shfl_xor(v, 8);
            if (lrow16 == 0) red[wid][mt * 16 + kgrp * 4 + r] = v;
        }
    __syncthreads();                      // red + all redc visible
    if (tid < BM) {                       // row sums -> slot c
        const int h = tid >> 6, l = tid & 63;
        partials[(size_t)c * N_TOTAL + bi * BM + tid] = red[h * 2][l] + red[h * 2 + 1][l];
    } else {                              // col sums -> slot 16+bi (per tile)
        const int col = tid - BM;         // 0..127
        const int wcc = col >> 6, l = col & 63;
        for (int t = 0; t < NT; ++t) {
            if (c == 0 && t == 0) continue;   // diag tile: no colacc
            partials[(size_t)(16 + bi) * N_TOTAL + (bj0 + t) * BM + col] =
                redc[t][wcc][l] + redc[t][2 + wcc][l];
        }
    }
}

// ---------------------------------------------------------------------------
// Kernel 3: per-row lse - pos.  FIXED unrolled 80-slot sum (R17's proven
// form — R18's variable-bound rolled loops were the serial tail).
// Unwritten slots are zero (nrmpos zeroing).  Subtracts fp8 diag via self.
// ---------------------------------------------------------------------------
__global__ __launch_bounds__(256) void lse_kernel(const float* __restrict__ partials,
                                                  const float* __restrict__ pos,
                                                  const float* __restrict__ self,
                                                  float* __restrict__ bsums) {
    int tid = threadIdx.x;
    int row = blockIdx.x * 256 + tid;
    float s = 0.0f;
#pragma unroll 8
    for (int c = 0; c < NSLOT; ++c) s += partials[(size_t)c * N_TOTAL + row];
    s -= __expf(self[row] - 2.0f);        // remove diagonal contribution
    float v = 2.0f + logf(s) - pos[row];
#pragma unroll
    for (int m = 32; m >= 1; m >>= 1) v += __shfl_xor(v, m);
    __shared__ float wsum[4];
    if ((tid & 63) == 0) wsum[tid >> 6] = v;
    __syncthreads();
    if (tid == 0) bsums[blockIdx.x] = wsum[0] + wsum[1] + wsum[2] + wsum[3];
}

__global__ void final_kernel(const float* __restrict__ bsums, float* __restrict__ out) {
    int tid = threadIdx.x;                // 64 threads
    float v = (tid < N_TOTAL / 256) ? bsums[tid] : 0.0f;
#pragma unroll
    for (int m = 32; m >= 1; m >>= 1) v += __shfl_xor(v, m);
    if (tid == 0) out[0] = v * (1.0f / (float)N_TOTAL);
}

// ---------------------------------------------------------------------------
extern "C" void kernel_launch(void* const* d_in, const int* in_sizes, int n_in,
                              void* d_out, int out_size, void* d_ws, size_t ws_size,
                              hipStream_t stream) {
    const float* z1 = (const float*)d_in[0];
    const float* z2 = (const float*)d_in[1];
    float* out = (float*)d_out;

    char* ws = (char*)d_ws;
    unsigned char* zn8 = (unsigned char*)ws;                               // 2 MB
    size_t off = (size_t)N_TOTAL * D_DIM;
    float* pos = (float*)(ws + off);                                       // 32 KB
    off += (size_t)N_TOTAL * sizeof(float);
    float* self = (float*)(ws + off);                                      // 32 KB
    off += (size_t)N_TOTAL * sizeof(float);
    float* partials = (float*)(ws + off);                                  // 2.62 MB
    off += (size_t)NSLOT * N_TOTAL * sizeof(float);
    float* bsums = (float*)(ws + off);                                     // 128 B

    nrmpos_kernel<<<B_HALF / 4, 256, 0, stream>>>(z1, z2, zn8, pos, self, partials);
    simexp_kernel<<<dim3(NB, 16), 256, 0, stream>>>(zn8, partials);
    lse_kernel<<<N_TOTAL / 256, 256, 0, stream>>>(partials, pos, self, bsums);
    final_kernel<<<1, 64, 0, stream>>>(bsums, out);
}

// Round 20
// 33.491 us; speedup vs baseline: 1.6300x; 1.3198x over previous
//
#include <hip/hip_runtime.h>

#define N_TOTAL 8192
#define B_HALF  4096
#define D_DIM   256
#define BM      128
#define CSPLIT  8
#define COLS_PER_SPLIT 1024
#define NTILE   8                     // 128-col B tiles per block

typedef __attribute__((ext_vector_type(4))) float f32x4;
typedef __attribute__((ext_vector_type(4))) int   int4v;
typedef __attribute__((ext_vector_type(8))) int   int8v;   // 32 fp8 = K=128 frag

// async global->LDS, 16B per lane (dest = wave-uniform base + lane*16)
#define GLOAD16(src, dst) __builtin_amdgcn_global_load_lds( \
    (const __attribute__((address_space(1))) unsigned int*)(src), \
    (__attribute__((address_space(3))) unsigned int*)(dst), 16, 0, 0)

// OCP e4m3fn decode (bias 7, 3-bit mantissa, subnormal scale 2^-6)
__device__ __forceinline__ float fp8_to_f32(unsigned b) {
    unsigned s = b >> 7, e = (b >> 3) & 15, m = b & 7;
    float mag = e ? (float)(8 + m) * __int_as_float((int)((e + 117) << 23))
                  : (float)m * 0.001953125f;            // m * 2^-9
    return s ? -mag : mag;
}

// ---------------------------------------------------------------------------
// Kernel 1: fused normalize + positive-pair sim + fp8 self-similarity.
// One WAVE per pair i.  zn8 rows natural k-order fp8, scaled by sqrt(2) so
// dot = 2*cos = s.  pos fp32 (unrounded); self = fp8-rounded self-dot so lse
// subtracts the diagonal exactly -> simexp is branch-free.
// ---------------------------------------------------------------------------
__global__ __launch_bounds__(256) void nrmpos_kernel(const float* __restrict__ z1,
                                                     const float* __restrict__ z2,
                                                     unsigned char* __restrict__ zn8,
                                                     float* __restrict__ pos,
                                                     float* __restrict__ self) {
    int i    = (blockIdx.x * 256 + threadIdx.x) >> 6;   // pair 0..4095
    int lane = threadIdx.x & 63;
    float4 a = reinterpret_cast<const float4*>(z1 + (size_t)i * D_DIM)[lane];
    float4 b = reinterpret_cast<const float4*>(z2 + (size_t)i * D_DIM)[lane];
    float ssa = a.x * a.x + a.y * a.y + a.z * a.z + a.w * a.w;
    float ssb = b.x * b.x + b.y * b.y + b.z * b.z + b.w * b.w;
    float dab = a.x * b.x + a.y * b.y + a.z * b.z + a.w * b.w;
#pragma unroll
    for (int m = 32; m >= 1; m >>= 1) {
        ssa += __shfl_xor(ssa, m);
        ssb += __shfl_xor(ssb, m);
        dab += __shfl_xor(dab, m);
    }
    float inva = 1.0f / fmaxf(sqrtf(ssa), 1e-8f);
    float invb = 1.0f / fmaxf(sqrtf(ssb), 1e-8f);
    float sa = 1.4142135623730951f * inva;
    float sb = 1.4142135623730951f * invb;
    int pa = __builtin_amdgcn_cvt_pk_fp8_f32(a.x * sa, a.y * sa, 0, false);
    pa     = __builtin_amdgcn_cvt_pk_fp8_f32(a.z * sa, a.w * sa, pa, true);
    int pb = __builtin_amdgcn_cvt_pk_fp8_f32(b.x * sb, b.y * sb, 0, false);
    pb     = __builtin_amdgcn_cvt_pk_fp8_f32(b.z * sb, b.w * sb, pb, true);
    float sa8 = 0.0f, sb8 = 0.0f;
#pragma unroll
    for (int u = 0; u < 4; ++u) {
        float da = fp8_to_f32((unsigned)(pa >> (8 * u)) & 0xff);
        float db = fp8_to_f32((unsigned)(pb >> (8 * u)) & 0xff);
        sa8 += da * da;
        sb8 += db * db;
    }
#pragma unroll
    for (int m = 32; m >= 1; m >>= 1) {
        sa8 += __shfl_xor(sa8, m);
        sb8 += __shfl_xor(sb8, m);
    }
    *reinterpret_cast<int*>(zn8 + (size_t)i * D_DIM + lane * 4)            = pa;
    *reinterpret_cast<int*>(zn8 + (size_t)(i + B_HALF) * D_DIM + lane * 4) = pb;
    if (lane == 0) {
        float pp = 2.0f * dab * inva * invb;
        pos[i]           = pp;
        pos[i + B_HALF]  = pp;
        self[i]          = sa8;
        self[i + B_HALF] = sb8;
    }
}

// ---------------------------------------------------------------------------
// Kernel 2: fused rowsum_i += sum_j exp(s_ij - 2) over ALL j (diag in lse).
// EXACT R12 champion engine (35.2 us total) with ONE arithmetic fold:
// accumulators are initialized to -2.0 (the MFMA C-input carries it through
// both k-chunks, so acc emerges as s-2) and the epilogue calls __expf(acc)
// directly — removes 67M v_sub from the serial exp phase (~1.7 us).
// Engine: MX-scaled MFMA 16x16x128 fp8 (scale=1.0 exact), 256 thr = 4 waves
// (2x2), 2 independent blocks/CU; A-frags in registers (aF[2][4], 64 VGPR);
// B dbuf 2x32 KB; bF loaded per-k-chunk inside the MFMA phase; order:
// MFMA -> barrier -> stage(t+2) -> exp (the R12 schedule, unmodified).
// B swizzle both-sides: cell c of row r at c^(r&15); read cell ^lrow16.
// ---------------------------------------------------------------------------
__global__ __launch_bounds__(256, 2) void simexp_kernel(const unsigned char* __restrict__ zn8,
                                                        float* __restrict__ partials) {
    __shared__ __attribute__((aligned(16))) unsigned char lB[2][BM * D_DIM];  // 64 KB
    __shared__ float red[4][64];

    const int bi = blockIdx.x;            // row strip (0..63)
    const int ci = blockIdx.y;            // col split (0..7)
    const int tid  = threadIdx.x;
    const int lane = tid & 63;
    const int wid  = tid >> 6;
    const int wr   = wid >> 1;            // wave row 0..1
    const int wc   = wid & 1;             // wave col 0..1
    const int lrow16 = lane & 15;
    const int kgrp   = lane >> 4;         // 0..3  (k-group of 32 within 128)

    const unsigned char* Abase  = zn8 + (size_t)bi * BM * D_DIM;
    const unsigned char* Bbase0 = zn8 + (size_t)ci * COLS_PER_SPLIT * D_DIM;

    // staging: 2048 granules of 16B per 32KB tile, 8 per thread, src-swizzled
    int soff[8];
#pragma unroll
    for (int u = 0; u < 8; ++u) {
        const int g = tid + u * 256;
        const int r = g >> 4, c = g & 15;
        soff[u] = r * D_DIM + ((c ^ (r & 15)) << 4);
    }
    auto stageB = [&](int t, int buf) {
        const unsigned char* Bb = Bbase0 + (size_t)t * BM * D_DIM;
#pragma unroll
        for (int u = 0; u < 8; ++u)
            GLOAD16(Bb + soff[u], lB[buf] + ((tid + u * 256) << 4));
    };

    // swizzled 32B frag load: row-local cells (ck*8 + kgrp*2 + {0,1}) ^ lrow16
    auto load32 = [&](const unsigned char* base, int row, int ck) -> int8v {
        const int c0 = ck * 8 + kgrp * 2;
        int4v lo = *reinterpret_cast<const int4v*>(
            base + row * D_DIM + (((c0 + 0) ^ lrow16) << 4));
        int4v hi = *reinterpret_cast<const int4v*>(
            base + row * D_DIM + (((c0 + 1) ^ lrow16) << 4));
        int8v r8;
        r8[0] = lo[0]; r8[1] = lo[1]; r8[2] = lo[2]; r8[3] = lo[3];
        r8[4] = hi[0]; r8[5] = hi[1]; r8[6] = hi[2]; r8[7] = hi[3];
        return r8;
    };

    // ---- prologue: A -> lB[1], B0 -> lB[0] ----
#pragma unroll
    for (int u = 0; u < 8; ++u)
        GLOAD16(Abase + soff[u], lB[1] + ((tid + u * 256) << 4));
    stageB(0, 0);
    __syncthreads();                      // A + B0 landed

    // hoist all 8 A fragments to registers (aF[ck][mt], 64 VGPR)
    int8v aF[2][4];
#pragma unroll
    for (int ck = 0; ck < 2; ++ck)
#pragma unroll
        for (int mt = 0; mt < 4; ++mt)
            aF[ck][mt] = load32(lB[1], wr * 64 + mt * 16 + lrow16, ck);
    __syncthreads();                      // all waves done: lB[1] free
    stageB(1, 1);                         // B1 in flight across tile 0 compute

    f32x4 acc[4][4];
    float rowacc[4][4];
#pragma unroll
    for (int mt = 0; mt < 4; ++mt)
#pragma unroll
        for (int nt = 0; nt < 4; ++nt) { acc[mt][nt] = (f32x4)(-2.0f); rowacc[mt][nt] = 0.0f; }

    for (int t = 0; t < NTILE; ++t) {
        const unsigned char* Bl = lB[t & 1];

        // ---- pure LDS+MFMA phase: 2 k-chunks x 16 mfma_scale ----
#pragma unroll
        for (int ck = 0; ck < 2; ++ck) {
            int8v bF[4];
#pragma unroll
            for (int nt = 0; nt < 4; ++nt)
                bF[nt] = load32(Bl, wc * 64 + nt * 16 + lrow16, ck);
#pragma unroll
            for (int mt = 0; mt < 4; ++mt)
#pragma unroll
                for (int nt = 0; nt < 4; ++nt)
                    acc[mt][nt] = __builtin_amdgcn_mfma_scale_f32_16x16x128_f8f6f4(
                        aF[ck][mt], bF[nt], acc[mt][nt],
                        0, 0, 0, 127, 0, 127);
        }

        if (t + 1 < NTILE) __syncthreads();      // B(t+1) landed; buf(t) reads done
        if (t + 2 < NTILE) stageB(t + 2, t & 1); // refill freed buffer

        // ---- register-only exp epilogue (acc already holds s - 2) ----
#pragma unroll
        for (int mt = 0; mt < 4; ++mt) {
#pragma unroll
            for (int r = 0; r < 4; ++r) {
                float s = 0.0f;
#pragma unroll
                for (int nt = 0; nt < 4; ++nt)
                    s += __expf(acc[mt][nt][r]);
                rowacc[mt][r] += s;
            }
#pragma unroll
            for (int nt = 0; nt < 4; ++nt) acc[mt][nt] = (f32x4)(-2.0f);
        }
    }

    // ---- block-end reduce across the 16 col-lanes ----
#pragma unroll
    for (int mt = 0; mt < 4; ++mt)
#pragma unroll
        for (int r = 0; r < 4; ++r) {
            float v = rowacc[mt][r];
            v += __shfl_xor(v, 1); v += __shfl_xor(v, 2);
            v += __shfl_xor(v, 4); v += __shfl_xor(v, 8);
            if (lrow16 == 0) red[wid][mt * 16 + kgrp * 4 + r] = v;
        }
    __syncthreads();
    if (tid < BM) {
        const int h = tid >> 6, l = tid & 63;
        partials[(size_t)ci * N_TOTAL + bi * BM + tid] = red[h * 2][l] + red[h * 2 + 1][l];
    }
}

// ---------------------------------------------------------------------------
// Kernel 3: per-row lse - pos (subtracting the fp8 diag term), block sums.
// ---------------------------------------------------------------------------
__global__ __launch_bounds__(256) void lse_kernel(const float* __restrict__ partials,
                                                  const float* __restrict__ pos,
                                                  const float* __restrict__ self,
                                                  float* __restrict__ bsums) {
    int tid = threadIdx.x;
    int row = blockIdx.x * 256 + tid;
    float s = 0.0f;
#pragma unroll
    for (int c = 0; c < CSPLIT; ++c) s += partials[(size_t)c * N_TOTAL + row];
    s -= __expf(self[row] - 2.0f);        // remove diagonal contribution
    float v = 2.0f + logf(s) - pos[row];
#pragma unroll
    for (int m = 32; m >= 1; m >>= 1) v += __shfl_xor(v, m);
    __shared__ float wsum[4];
    if ((tid & 63) == 0) wsum[tid >> 6] = v;
    __syncthreads();
    if (tid == 0) bsums[blockIdx.x] = wsum[0] + wsum[1] + wsum[2] + wsum[3];
}

__global__ void final_kernel(const float* __restrict__ bsums, float* __restrict__ out) {
    int tid = threadIdx.x;                // 64 threads
    float v = (tid < N_TOTAL / 256) ? bsums[tid] : 0.0f;
#pragma unroll
    for (int m = 32; m >= 1; m >>= 1) v += __shfl_xor(v, m);
    if (tid == 0) out[0] = v * (1.0f / (float)N_TOTAL);
}

// ---------------------------------------------------------------------------
extern "C" void kernel_launch(void* const* d_in, const int* in_sizes, int n_in,
                              void* d_out, int out_size, void* d_ws, size_t ws_size,
                              hipStream_t stream) {
    const float* z1 = (const float*)d_in[0];
    const float* z2 = (const float*)d_in[1];
    float* out = (float*)d_out;

    char* ws = (char*)d_ws;
    unsigned char* zn8 = (unsigned char*)ws;                               // 2 MB
    size_t off = (size_t)N_TOTAL * D_DIM;
    float* pos = (float*)(ws + off);                                       // 32 KB
    off += (size_t)N_TOTAL * sizeof(float);
    float* self = (float*)(ws + off);                                      // 32 KB
    off += (size_t)N_TOTAL * sizeof(float);
    float* partials = (float*)(ws + off);                                  // 256 KB
    off += (size_t)CSPLIT * N_TOTAL * sizeof(float);
    float* bsums = (float*)(ws + off);                                     // 128 B

    nrmpos_kernel<<<B_HALF / 4, 256, 0, stream>>>(z1, z2, zn8, pos, self);
    simexp_kernel<<<dim3(N_TOTAL / BM, CSPLIT), 256, 0, stream>>>(zn8, partials);
    lse_kernel<<<N_TOTAL / 256, 256, 0, stream>>>(partials, pos, self, bsums);
    final_kernel<<<1, 64, 0, stream>>>(bsums, out);
}